// Round 7
// baseline (215.799 us; speedup 1.0000x reference)
//
#include <hip/hip_runtime.h>
#include <math.h>

typedef __bf16 bf16x8 __attribute__((ext_vector_type(8)));
typedef float  f32x4  __attribute__((ext_vector_type(4)));
typedef unsigned short u16x4 __attribute__((ext_vector_type(4)));

#define BATCH  2
#define SEQ    2048
#define DMODEL 1024
#define NHEAD  16
#define DHEAD  64
#define MROWS  4096
#define N_QKV  3072
#define KDIM   1024
#define OUTSECT (MROWS*DMODEL)   // 4194304 elements

#define LOG2E 1.44269504088896f
#define QSCALE (0.125f * LOG2E)  // folded into qb at GEMM1 epilogue

__device__ inline __bf16 f2bf(float f) {
    unsigned u = __builtin_bit_cast(unsigned, f);
    unsigned r = (u + 0x7fffu + ((u >> 16) & 1u)) >> 16;
    return __builtin_bit_cast(__bf16, (unsigned short)r);
}

// async global->LDS, 16B per lane; LDS dest is wave-uniform base + lane*16
__device__ inline void gload16(const void* g, void* l) {
    __builtin_amdgcn_global_load_lds(
        (const __attribute__((address_space(1))) void*)g,
        (__attribute__((address_space(3))) void*)l, 16, 0, 0);
}

// 16-lane (DPP row) reductions: ^1, ^2, ror:8(=^8), row_mirror (closes quads)
__device__ inline float dpp_max16(float x) {
    int v, t;
    v = __builtin_bit_cast(int, x);
    t = __builtin_amdgcn_update_dpp(v, v, 0xB1, 0xF, 0xF, false);   // quad_perm ^1
    x = fmaxf(x, __builtin_bit_cast(float, t));
    v = __builtin_bit_cast(int, x);
    t = __builtin_amdgcn_update_dpp(v, v, 0x4E, 0xF, 0xF, false);   // quad_perm ^2
    x = fmaxf(x, __builtin_bit_cast(float, t));
    v = __builtin_bit_cast(int, x);
    t = __builtin_amdgcn_update_dpp(v, v, 0x128, 0xF, 0xF, false);  // row_ror:8
    x = fmaxf(x, __builtin_bit_cast(float, t));
    v = __builtin_bit_cast(int, x);
    t = __builtin_amdgcn_update_dpp(v, v, 0x140, 0xF, 0xF, false);  // row_mirror
    x = fmaxf(x, __builtin_bit_cast(float, t));
    return x;
}
__device__ inline float dpp_sum16(float x) {
    int v, t;
    v = __builtin_bit_cast(int, x);
    t = __builtin_amdgcn_update_dpp(v, v, 0xB1, 0xF, 0xF, false);
    x += __builtin_bit_cast(float, t);
    v = __builtin_bit_cast(int, x);
    t = __builtin_amdgcn_update_dpp(v, v, 0x4E, 0xF, 0xF, false);
    x += __builtin_bit_cast(float, t);
    v = __builtin_bit_cast(int, x);
    t = __builtin_amdgcn_update_dpp(v, v, 0x128, 0xF, 0xF, false);
    x += __builtin_bit_cast(float, t);
    v = __builtin_bit_cast(int, x);
    t = __builtin_amdgcn_update_dpp(v, v, 0x140, 0xF, 0xF, false);
    x += __builtin_bit_cast(float, t);
    return x;
}

// ---------------- fused conversion kernel (1 launch) ----------------
__global__ __launch_bounds__(256) void cvt_all_k(
    const float* __restrict__ x, __bf16* __restrict__ xb,
    const float* __restrict__ W_in, __bf16* __restrict__ wti,
    const float* __restrict__ W_out, __bf16* __restrict__ wto)
{
    __shared__ float t[64][65];
    const int b = blockIdx.x;
    const int tid = threadIdx.x;
    if (b < 2048) {
        size_t i = (size_t)b * 256 + tid;
        const float4* p = (const float4*)x + i * 2;
        float4 a = p[0], c = p[1];
        __bf16 o[8] = {f2bf(a.x), f2bf(a.y), f2bf(a.z), f2bf(a.w),
                       f2bf(c.x), f2bf(c.y), f2bf(c.z), f2bf(c.w)};
        *(bf16x8*)(xb + i * 8) = *(bf16x8*)o;
        return;
    }
    const float* W;  __bf16* Wt;  int Nw, bx, by;
    if (b < 2816) { int c = b - 2048; W = W_in;  Wt = wti; Nw = N_QKV;  bx = c % 48; by = c / 48; }
    else          { int c = b - 2816; W = W_out; Wt = wto; Nw = DMODEL; bx = c % 16; by = c / 16; }
    const int k0 = by * 64, n0 = bx * 64;
    #pragma unroll
    for (int u = 0; u < 4; ++u) {
        int idx = u * 256 + tid;
        int r = idx >> 4, c4 = (idx & 15) << 2;
        float4 v = *(const float4*)&W[(size_t)(k0 + r) * Nw + n0 + c4];
        t[r][c4] = v.x; t[r][c4 + 1] = v.y; t[r][c4 + 2] = v.z; t[r][c4 + 3] = v.w;
    }
    __syncthreads();
    #pragma unroll
    for (int u = 0; u < 2; ++u) {
        int idx = u * 256 + tid;
        int n = idx >> 3, k8 = (idx & 7) << 3;
        __bf16 o[8];
        #pragma unroll
        for (int i = 0; i < 8; ++i) o[i] = f2bf(t[k8 + i][n]);
        *(bf16x8*)&Wt[(size_t)(n0 + n) * KDIM + k0 + k8] = *(bf16x8*)o;
    }
}

// ---------------- GEMM: A[M][1024] bf16 row-major, Bt[N][1024] bf16 row-major
template<int MODE, int FI, int FJ>
__global__ __launch_bounds__(256) void gemm_bf(
    const __bf16* __restrict__ A, const __bf16* __restrict__ Bt,
    const float* __restrict__ bias,
    float* __restrict__ fo, float* __restrict__ kf, float* __restrict__ vf,
    __bf16* __restrict__ qb, __bf16* __restrict__ kb, __bf16* __restrict__ vb,
    int nbx)
{
    constexpr int BMt = FI * 32, BNt = FJ * 32;
    __shared__ __align__(16) __bf16 As[BMt * 64];
    __shared__ __align__(16) __bf16 Bs[BNt * 64];

    const int tid = threadIdx.x, wid = tid >> 6, lane = tid & 63;
    const int l16 = lane & 15, lq = lane >> 4;
    const int wm = wid >> 1, wn = wid & 1;

    const int nwg = gridDim.x;
    const int bid = blockIdx.x;
    const int swz = (bid & 7) * (nwg >> 3) + (bid >> 3);
    const int m0 = (swz / nbx) * BMt;
    const int n0 = (swz % nbx) * BNt;

    const int lr8 = lane >> 3;
    const int colE = ((lane & 7) ^ lr8) << 3;

    f32x4 acc[FI][FJ];
    #pragma unroll
    for (int i = 0; i < FI; ++i)
        #pragma unroll
        for (int j = 0; j < FJ; ++j)
            acc[i][j] = f32x4{0.f, 0.f, 0.f, 0.f};

    for (int k0 = 0; k0 < KDIM; k0 += 64) {
        __syncthreads();
        #pragma unroll
        for (int c = wid; c < FI * 4 + FJ * 4; c += 4) {
            const bool isA = (c < FI * 4);
            const int ch = isA ? c : c - FI * 4;
            const int row = ch * 8 + lr8;
            const __bf16* src = isA ? (A  + (size_t)(m0 + row) * KDIM + k0 + colE)
                                    : (Bt + (size_t)(n0 + row) * KDIM + k0 + colE);
            gload16(src, (isA ? As : Bs) + ch * 512);
        }
        __syncthreads();
        #pragma unroll
        for (int kk = 0; kk < 2; ++kk) {
            bf16x8 af[FI], bfg[FJ];
            #pragma unroll
            for (int i = 0; i < FI; ++i) {
                int r = wm * (FI * 16) + i * 16 + l16;
                af[i] = *(const bf16x8*)&As[r * 64 + ((kk * 32 + lq * 8) ^ ((r & 7) << 3))];
            }
            #pragma unroll
            for (int j = 0; j < FJ; ++j) {
                int r = wn * (FJ * 16) + j * 16 + l16;
                bfg[j] = *(const bf16x8*)&Bs[r * 64 + ((kk * 32 + lq * 8) ^ ((r & 7) << 3))];
            }
            #pragma unroll
            for (int i = 0; i < FI; ++i)
                #pragma unroll
                for (int j = 0; j < FJ; ++j)
                    acc[i][j] = __builtin_amdgcn_mfma_f32_16x16x32_bf16(af[i], bfg[j], acc[i][j], 0, 0, 0);
        }
    }

    #pragma unroll
    for (int i = 0; i < FI; ++i) {
        #pragma unroll
        for (int j = 0; j < FJ; ++j) {
            const int col  = n0 + wn * (FJ * 16) + j * 16 + l16;
            const int rowb = m0 + wm * (FI * 16) + i * 16 + lq * 4;
            float v[4];
            #pragma unroll
            for (int r = 0; r < 4; ++r) v[r] = acc[i][j][r] + bias[col];
            if (MODE == 1) {
                #pragma unroll
                for (int r = 0; r < 4; ++r)
                    fo[(size_t)(rowb + r) * DMODEL + col] = v[r];
            } else {
                const int which = col >> 10, rem = col & 1023;
                const int h = rem >> 6, dh = rem & 63;
                const int bb = rowb >> 11, ll = rowb & 2047;
                const size_t lidx = ((size_t)(bb * NHEAD + h) * SEQ + ll) * DHEAD + dh;
                if (which == 0) {
                    #pragma unroll
                    for (int r = 0; r < 4; ++r)
                        qb[lidx + (size_t)r * DHEAD] = f2bf(v[r] * QSCALE);
                } else if (which == 1) {
                    #pragma unroll
                    for (int r = 0; r < 4; ++r) {
                        kf[lidx + (size_t)r * DHEAD] = v[r];
                        kb[lidx + (size_t)r * DHEAD] = f2bf(v[r]);
                    }
                } else {
                    u16x4 pk;
                    #pragma unroll
                    for (int r = 0; r < 4; ++r) {
                        vf[lidx + (size_t)r * DHEAD] = v[r];
                        pk[r] = __builtin_bit_cast(unsigned short, f2bf(v[r]));
                    }
                    *(u16x4*)&vb[((size_t)(bb * NHEAD + h) * DHEAD + dh) * SEQ + ll] = pk;
                }
            }
        }
    }
}

// ---------------- flash attention (round 7: QBLK=128, 8 waves, 2 blocks/CU)
// Qb pre-scaled by 0.125*log2e; Kb [B,H,L,Dh]; Vb [B,H,Dh,L] bf16.
__global__ __launch_bounds__(512) void attn_k(
    const __bf16* __restrict__ Qb, const __bf16* __restrict__ Kb,
    const __bf16* __restrict__ Vb, __bf16* __restrict__ Ob)
{
    __shared__ __align__(16) __bf16 Qs[128 * 64];      // 16 KB
    __shared__ __align__(16) __bf16 Ks[2][64 * 64];    // 16 KB
    __shared__ __align__(16) __bf16 Vs[2][64 * 64];    // 16 KB  [dh][kv]
    __shared__ __align__(16) __bf16 Ps[8 * 16 * 64];   // 16 KB

    const int tid = threadIdx.x, wid = tid >> 6, lane = tid & 63;
    const int l16 = lane & 15, lq = lane >> 4;

    // 512 blocks: xcd = bid&7 owns 4 bh; within XCD, consecutive launch pairs are
    // (long, short) q-chunks of the SAME bh -> per-CU work balanced, K/V L2-local.
    const int bid = blockIdx.x;
    const int j   = bid >> 3;
    const int p   = j >> 1, half = j & 1;
    const int bh  = (bid & 7) * 4 + (p & 3);
    const int q2i = p >> 2;                 // 0..7
    const int qt2 = half ? q2i : (15 - q2i);
    const int h = bh & 15, bb = bh >> 4;
    const int q0b  = qt2 * 128;
    const int jtop = 2 * qt2 + 1;
    const size_t kvbase = (size_t)bh * SEQ * DHEAD;
    const float slope2 = exp2f(-0.5f * (float)(h + 1)) * LOG2E;
    const int qa = q0b + wid * 16;          // wave's first q row (global)
    const int lr8 = lane >> 3;
    const int colE = ((lane & 7) ^ lr8) << 3;

    // stage Q (16 chunks of 8 rows; wave wid does chunks 2wid, 2wid+1)
    #pragma unroll
    for (int u = 0; u < 2; ++u) {
        int ch = wid * 2 + u;
        int row = ch * 8 + lr8;
        gload16(Qb + kvbase + (size_t)(q0b + row) * DHEAD + colE, Qs + ch * 512);
    }
    // stage K/V tile 0 (8 chunks each; wave wid does chunk wid)
    {
        int row = wid * 8 + lr8;
        gload16(Kb + kvbase + (size_t)row * DHEAD + colE, Ks[0] + wid * 512);
        gload16(Vb + kvbase + (size_t)row * SEQ  + colE, Vs[0] + wid * 512);
    }
    __syncthreads();

    // hoisted Q fragments (Qs is read-only afterwards)
    const int qrow = wid * 16 + l16;
    const bf16x8 aq0 = *(const bf16x8*)&Qs[qrow * 64 + ((lq * 8) ^ ((qrow & 7) << 3))];
    const bf16x8 aq1 = *(const bf16x8*)&Qs[qrow * 64 + ((32 + lq * 8) ^ ((qrow & 7) << 3))];

    // base ALiBi bias (jt=0): ct = slope2*((nf*16+l16) - qi); per-tile s = ct + jt*dtj
    float ct[4][4];
    #pragma unroll
    for (int r = 0; r < 4; ++r) {
        const int qi = qa + lq * 4 + r;
        #pragma unroll
        for (int nf = 0; nf < 4; ++nf)
            ct[r][nf] = slope2 * (float)(nf * 16 + l16 - qi);
    }
    const float dtj = slope2 * 64.f;

    float mrow[4], lrow[4];
    f32x4 accO[4];
    #pragma unroll
    for (int r = 0; r < 4; ++r) { mrow[r] = -1e30f; lrow[r] = 0.f; }
    #pragma unroll
    for (int jj = 0; jj < 4; ++jj) accO[jj] = f32x4{0.f, 0.f, 0.f, 0.f};

    int cur = 0;
    for (int jt = 0; jt <= jtop; ++jt) {
        const int j0 = jt * 64;

        // async prefetch next K/V tile (all waves, even if compute-skipped)
        if (jt < jtop) {
            const int jn = j0 + 64;
            int row = wid * 8 + lr8;
            gload16(Kb + kvbase + (size_t)(jn + row) * DHEAD + colE, Ks[cur ^ 1] + wid * 512);
            gload16(Vb + kvbase + (size_t)row * SEQ + jn + colE,     Vs[cur ^ 1] + wid * 512);
        }

        // wave-uniform skip: this wave's rows all < j0 -> tile fully masked
        if (qa + 16 > j0) {
            const float tb = dtj * (float)jt;
            f32x4 s[4];
            #pragma unroll
            for (int nf = 0; nf < 4; ++nf)
                #pragma unroll
                for (int r = 0; r < 4; ++r) s[nf][r] = ct[r][nf] + tb;
            if (qa < j0 + 64) {
                // diagonal for this wave: mask ki > qi, rel = qa - j0 in {0,16,32,48}
                const int rel = qa - j0;
                #pragma unroll
                for (int nf = 0; nf < 4; ++nf)
                    #pragma unroll
                    for (int r = 0; r < 4; ++r)
                        if (nf * 16 + l16 > rel + lq * 4 + r) s[nf][r] = -3e38f;
            }

            __builtin_amdgcn_s_setprio(1);
            #pragma unroll
            for (int nf = 0; nf < 4; ++nf) {
                int kr = nf * 16 + l16;
                bf16x8 bk0 = *(const bf16x8*)&Ks[cur][kr * 64 + ((lq * 8) ^ ((kr & 7) << 3))];
                bf16x8 bk1 = *(const bf16x8*)&Ks[cur][kr * 64 + ((32 + lq * 8) ^ ((kr & 7) << 3))];
                s[nf] = __builtin_amdgcn_mfma_f32_16x16x32_bf16(aq0, bk0, s[nf], 0, 0, 0);
                s[nf] = __builtin_amdgcn_mfma_f32_16x16x32_bf16(aq1, bk1, s[nf], 0, 0, 0);
            }
            __builtin_amdgcn_s_setprio(0);

            // online softmax, log2 domain, DPP reductions, defer-max (THR=8)
            float rm[4];
            #pragma unroll
            for (int r = 0; r < 4; ++r)
                rm[r] = dpp_max16(fmaxf(fmaxf(s[0][r], s[1][r]), fmaxf(s[2][r], s[3][r])));
            bool need = (rm[0] > mrow[0] + 8.f) || (rm[1] > mrow[1] + 8.f) ||
                        (rm[2] > mrow[2] + 8.f) || (rm[3] > mrow[3] + 8.f);
            if (__any(need)) {
                #pragma unroll
                for (int r = 0; r < 4; ++r) {
                    float mnew = fmaxf(mrow[r], rm[r]);
                    float scale = __builtin_amdgcn_exp2f(mrow[r] - mnew);
                    lrow[r] *= scale;
                    mrow[r] = mnew;
                    #pragma unroll
                    for (int nf = 0; nf < 4; ++nf) accO[nf][r] *= scale;
                }
            }
            #pragma unroll
            for (int r = 0; r < 4; ++r) {
                float p0 = __builtin_amdgcn_exp2f(s[0][r] - mrow[r]);
                float p1 = __builtin_amdgcn_exp2f(s[1][r] - mrow[r]);
                float p2 = __builtin_amdgcn_exp2f(s[2][r] - mrow[r]);
                float p3 = __builtin_amdgcn_exp2f(s[3][r] - mrow[r]);
                const int prow = lq * 4 + r;
                const int pb = wid * 1024 + prow * 64;
                const int px = (prow & 7) << 3;
                Ps[pb + ((l16     ) ^ px)] = (__bf16)p0;
                Ps[pb + ((l16 + 16) ^ px)] = (__bf16)p1;
                Ps[pb + ((l16 + 32) ^ px)] = (__bf16)p2;
                Ps[pb + ((l16 + 48) ^ px)] = (__bf16)p3;
                lrow[r] += dpp_sum16((p0 + p1) + (p2 + p3));
            }

            // O += P V
            bf16x8 ap0 = *(const bf16x8*)&Ps[wid * 1024 + l16 * 64 + ((lq * 8) ^ ((l16 & 7) << 3))];
            bf16x8 ap1 = *(const bf16x8*)&Ps[wid * 1024 + l16 * 64 + ((32 + lq * 8) ^ ((l16 & 7) << 3))];
            __builtin_amdgcn_s_setprio(1);
            #pragma unroll
            for (int nf = 0; nf < 4; ++nf) {
                int vr = nf * 16 + l16;
                bf16x8 bv0 = *(const bf16x8*)&Vs[cur][vr * 64 + ((lq * 8) ^ ((vr & 7) << 3))];
                bf16x8 bv1 = *(const bf16x8*)&Vs[cur][vr * 64 + ((32 + lq * 8) ^ ((vr & 7) << 3))];
                accO[nf] = __builtin_amdgcn_mfma_f32_16x16x32_bf16(ap0, bv0, accO[nf], 0, 0, 0);
                accO[nf] = __builtin_amdgcn_mfma_f32_16x16x32_bf16(ap1, bv1, accO[nf], 0, 0, 0);
            }
            __builtin_amdgcn_s_setprio(0);
        }

        __syncthreads();
        cur ^= 1;
    }

    #pragma unroll
    for (int r = 0; r < 4; ++r) {
        const float inv = __builtin_amdgcn_rcpf(lrow[r]);
        const int qi = qa + lq * 4 + r;
        #pragma unroll
        for (int nf = 0; nf < 4; ++nf) {
            int dh = nf * 16 + l16;
            Ob[(size_t)(bb * SEQ + qi) * DMODEL + h * DHEAD + dh] = (__bf16)(accO[nf][r] * inv);
        }
    }
}

extern "C" void kernel_launch(void* const* d_in, const int* in_sizes, int n_in,
                              void* d_out, int out_size, void* d_ws, size_t ws_size,
                              hipStream_t stream) {
    const float* x     = (const float*)d_in[0];
    const float* W_in  = (const float*)d_in[1];
    const float* b_in  = (const float*)d_in[2];
    const float* W_out = (const float*)d_in[3];
    const float* b_out = (const float*)d_in[4];

    float* out = (float*)d_out;
    float* kf  = out + (size_t)OUTSECT;
    float* vf  = out + 2 * (size_t)OUTSECT;

    __bf16* qb = (__bf16*)d_out;                   // scratch in d_out sec 0
    __bf16* xb = (__bf16*)d_out + (size_t)OUTSECT;

    __bf16* ob  = (__bf16*)d_ws;                   // 8 MB
    __bf16* kb  = ob + (size_t)OUTSECT;            // 8 MB
    __bf16* vb  = kb + (size_t)OUTSECT;            // 8 MB [B,H,Dh,L]
    __bf16* wti = vb + (size_t)OUTSECT;            // 6 MB
    __bf16* wto = wti + (size_t)N_QKV * KDIM;      // 2 MB

    cvt_all_k<<<3072, 256, 0, stream>>>(x, xb, W_in, wti, W_out, wto);

    gemm_bf<0, 4, 4><<<768, 256, 0, stream>>>(xb, wti, b_in,
        nullptr, kf, vf, qb, kb, vb, N_QKV / 128);

    attn_k<<<512, 512, 0, stream>>>(qb, kb, vb, ob);

    gemm_bf<1, 4, 4><<<256, 256, 0, stream>>>(ob, wto, b_out,
        out, nullptr, nullptr, nullptr, nullptr, nullptr, DMODEL / 128);
}

// Round 8
// 202.311 us; speedup vs baseline: 1.0667x; 1.0667x over previous
//
#include <hip/hip_runtime.h>
#include <math.h>

typedef __bf16 bf16x8 __attribute__((ext_vector_type(8)));
typedef float  f32x4  __attribute__((ext_vector_type(4)));
typedef unsigned short u16x4 __attribute__((ext_vector_type(4)));

#define BATCH  2
#define SEQ    2048
#define DMODEL 1024
#define NHEAD  16
#define DHEAD  64
#define MROWS  4096
#define N_QKV  3072
#define KDIM   1024
#define OUTSECT (MROWS*DMODEL)   // 4194304 elements

#define LOG2E 1.44269504088896f
#define QSCALE (0.125f * LOG2E)  // folded into qb at GEMM1 epilogue

__device__ inline __bf16 f2bf(float f) {
    unsigned u = __builtin_bit_cast(unsigned, f);
    unsigned r = (u + 0x7fffu + ((u >> 16) & 1u)) >> 16;
    return __builtin_bit_cast(__bf16, (unsigned short)r);
}

// async global->LDS, 16B per lane; LDS dest is wave-uniform base + lane*16
__device__ inline void gload16(const void* g, void* l) {
    __builtin_amdgcn_global_load_lds(
        (const __attribute__((address_space(1))) void*)g,
        (__attribute__((address_space(3))) void*)l, 16, 0, 0);
}

// 16-lane (DPP row) reductions: ^1, ^2, ror:8(=^8), row_mirror (closes quads)
__device__ inline float dpp_max16(float x) {
    int v, t;
    v = __builtin_bit_cast(int, x);
    t = __builtin_amdgcn_update_dpp(v, v, 0xB1, 0xF, 0xF, false);   // quad_perm ^1
    x = fmaxf(x, __builtin_bit_cast(float, t));
    v = __builtin_bit_cast(int, x);
    t = __builtin_amdgcn_update_dpp(v, v, 0x4E, 0xF, 0xF, false);   // quad_perm ^2
    x = fmaxf(x, __builtin_bit_cast(float, t));
    v = __builtin_bit_cast(int, x);
    t = __builtin_amdgcn_update_dpp(v, v, 0x128, 0xF, 0xF, false);  // row_ror:8
    x = fmaxf(x, __builtin_bit_cast(float, t));
    v = __builtin_bit_cast(int, x);
    t = __builtin_amdgcn_update_dpp(v, v, 0x140, 0xF, 0xF, false);  // row_mirror
    x = fmaxf(x, __builtin_bit_cast(float, t));
    return x;
}
__device__ inline float dpp_sum16(float x) {
    int v, t;
    v = __builtin_bit_cast(int, x);
    t = __builtin_amdgcn_update_dpp(v, v, 0xB1, 0xF, 0xF, false);
    x += __builtin_bit_cast(float, t);
    v = __builtin_bit_cast(int, x);
    t = __builtin_amdgcn_update_dpp(v, v, 0x4E, 0xF, 0xF, false);
    x += __builtin_bit_cast(float, t);
    v = __builtin_bit_cast(int, x);
    t = __builtin_amdgcn_update_dpp(v, v, 0x128, 0xF, 0xF, false);
    x += __builtin_bit_cast(float, t);
    v = __builtin_bit_cast(int, x);
    t = __builtin_amdgcn_update_dpp(v, v, 0x140, 0xF, 0xF, false);
    x += __builtin_bit_cast(float, t);
    return x;
}

// ---------------- fused conversion kernel (1 launch) ----------------
__global__ __launch_bounds__(256) void cvt_all_k(
    const float* __restrict__ x, __bf16* __restrict__ xb,
    const float* __restrict__ W_in, __bf16* __restrict__ wti,
    const float* __restrict__ W_out, __bf16* __restrict__ wto)
{
    __shared__ float t[64][65];
    const int b = blockIdx.x;
    const int tid = threadIdx.x;
    if (b < 2048) {
        size_t i = (size_t)b * 256 + tid;
        const float4* p = (const float4*)x + i * 2;
        float4 a = p[0], c = p[1];
        __bf16 o[8] = {f2bf(a.x), f2bf(a.y), f2bf(a.z), f2bf(a.w),
                       f2bf(c.x), f2bf(c.y), f2bf(c.z), f2bf(c.w)};
        *(bf16x8*)(xb + i * 8) = *(bf16x8*)o;
        return;
    }
    const float* W;  __bf16* Wt;  int Nw, bx, by;
    if (b < 2816) { int c = b - 2048; W = W_in;  Wt = wti; Nw = N_QKV;  bx = c % 48; by = c / 48; }
    else          { int c = b - 2816; W = W_out; Wt = wto; Nw = DMODEL; bx = c % 16; by = c / 16; }
    const int k0 = by * 64, n0 = bx * 64;
    #pragma unroll
    for (int u = 0; u < 4; ++u) {
        int idx = u * 256 + tid;
        int r = idx >> 4, c4 = (idx & 15) << 2;
        float4 v = *(const float4*)&W[(size_t)(k0 + r) * Nw + n0 + c4];
        t[r][c4] = v.x; t[r][c4 + 1] = v.y; t[r][c4 + 2] = v.z; t[r][c4 + 3] = v.w;
    }
    __syncthreads();
    #pragma unroll
    for (int u = 0; u < 2; ++u) {
        int idx = u * 256 + tid;
        int n = idx >> 3, k8 = (idx & 7) << 3;
        __bf16 o[8];
        #pragma unroll
        for (int i = 0; i < 8; ++i) o[i] = f2bf(t[k8 + i][n]);
        *(bf16x8*)&Wt[(size_t)(n0 + n) * KDIM + k0 + k8] = *(bf16x8*)o;
    }
}

// ---------------- GEMM: A[M][1024] bf16 row-major, Bt[N][1024] bf16 row-major
template<int MODE, int FI, int FJ>
__global__ __launch_bounds__(256) void gemm_bf(
    const __bf16* __restrict__ A, const __bf16* __restrict__ Bt,
    const float* __restrict__ bias,
    float* __restrict__ fo, float* __restrict__ kf, float* __restrict__ vf,
    __bf16* __restrict__ qb, __bf16* __restrict__ kb, __bf16* __restrict__ vb,
    int nbx)
{
    constexpr int BMt = FI * 32, BNt = FJ * 32;
    __shared__ __align__(16) __bf16 As[BMt * 64];
    __shared__ __align__(16) __bf16 Bs[BNt * 64];

    const int tid = threadIdx.x, wid = tid >> 6, lane = tid & 63;
    const int l16 = lane & 15, lq = lane >> 4;
    const int wm = wid >> 1, wn = wid & 1;

    const int nwg = gridDim.x;
    const int bid = blockIdx.x;
    const int swz = (bid & 7) * (nwg >> 3) + (bid >> 3);
    const int m0 = (swz / nbx) * BMt;
    const int n0 = (swz % nbx) * BNt;

    const int lr8 = lane >> 3;
    const int colE = ((lane & 7) ^ lr8) << 3;

    f32x4 acc[FI][FJ];
    #pragma unroll
    for (int i = 0; i < FI; ++i)
        #pragma unroll
        for (int j = 0; j < FJ; ++j)
            acc[i][j] = f32x4{0.f, 0.f, 0.f, 0.f};

    for (int k0 = 0; k0 < KDIM; k0 += 64) {
        __syncthreads();
        #pragma unroll
        for (int c = wid; c < FI * 4 + FJ * 4; c += 4) {
            const bool isA = (c < FI * 4);
            const int ch = isA ? c : c - FI * 4;
            const int row = ch * 8 + lr8;
            const __bf16* src = isA ? (A  + (size_t)(m0 + row) * KDIM + k0 + colE)
                                    : (Bt + (size_t)(n0 + row) * KDIM + k0 + colE);
            gload16(src, (isA ? As : Bs) + ch * 512);
        }
        __syncthreads();
        #pragma unroll
        for (int kk = 0; kk < 2; ++kk) {
            bf16x8 af[FI], bfg[FJ];
            #pragma unroll
            for (int i = 0; i < FI; ++i) {
                int r = wm * (FI * 16) + i * 16 + l16;
                af[i] = *(const bf16x8*)&As[r * 64 + ((kk * 32 + lq * 8) ^ ((r & 7) << 3))];
            }
            #pragma unroll
            for (int j = 0; j < FJ; ++j) {
                int r = wn * (FJ * 16) + j * 16 + l16;
                bfg[j] = *(const bf16x8*)&Bs[r * 64 + ((kk * 32 + lq * 8) ^ ((r & 7) << 3))];
            }
            #pragma unroll
            for (int i = 0; i < FI; ++i)
                #pragma unroll
                for (int j = 0; j < FJ; ++j)
                    acc[i][j] = __builtin_amdgcn_mfma_f32_16x16x32_bf16(af[i], bfg[j], acc[i][j], 0, 0, 0);
        }
    }

    #pragma unroll
    for (int i = 0; i < FI; ++i) {
        #pragma unroll
        for (int j = 0; j < FJ; ++j) {
            const int col  = n0 + wn * (FJ * 16) + j * 16 + l16;
            const int rowb = m0 + wm * (FI * 16) + i * 16 + lq * 4;
            float v[4];
            #pragma unroll
            for (int r = 0; r < 4; ++r) v[r] = acc[i][j][r] + bias[col];
            if (MODE == 1) {
                #pragma unroll
                for (int r = 0; r < 4; ++r)
                    fo[(size_t)(rowb + r) * DMODEL + col] = v[r];
            } else {
                const int which = col >> 10, rem = col & 1023;
                const int h = rem >> 6, dh = rem & 63;
                const int bb = rowb >> 11, ll = rowb & 2047;
                const size_t lidx = ((size_t)(bb * NHEAD + h) * SEQ + ll) * DHEAD + dh;
                if (which == 0) {
                    #pragma unroll
                    for (int r = 0; r < 4; ++r)
                        qb[lidx + (size_t)r * DHEAD] = f2bf(v[r] * QSCALE);
                } else if (which == 1) {
                    #pragma unroll
                    for (int r = 0; r < 4; ++r) {
                        kf[lidx + (size_t)r * DHEAD] = v[r];
                        kb[lidx + (size_t)r * DHEAD] = f2bf(v[r]);
                    }
                } else {
                    u16x4 pk;
                    #pragma unroll
                    for (int r = 0; r < 4; ++r) {
                        vf[lidx + (size_t)r * DHEAD] = v[r];
                        pk[r] = __builtin_bit_cast(unsigned short, f2bf(v[r]));
                    }
                    *(u16x4*)&vb[((size_t)(bb * NHEAD + h) * DHEAD + dh) * SEQ + ll] = pk;
                }
            }
        }
    }
}

// ---------------- flash attention (round 8: r6 structure + Qs/Ps union (40KB
// -> 4 blocks/CU), Q-fragment hoist, per-CU-balanced static qt mapping)
// Qb pre-scaled by 0.125*log2e; Kb [B,H,L,Dh]; Vb [B,H,Dh,L] bf16.
__global__ __launch_bounds__(256) void attn_k(
    const __bf16* __restrict__ Qb, const __bf16* __restrict__ Kb,
    const __bf16* __restrict__ Vb, __bf16* __restrict__ Ob)
{
    // QP: Q staging (64x64) consumed into regs once, then reused as the P
    // buffer. Wave w's P strip == wave w's own Q rows (16w..16w+15); same-wave
    // DS ops are in-order, so the overlap is race-free.
    __shared__ __align__(16) __bf16 QP[4096];          // 8 KB
    __shared__ __align__(16) __bf16 Ks[2][64 * 64];    // 16 KB
    __shared__ __align__(16) __bf16 Vs[2][64 * 64];    // 16 KB  [dh][kv]
    // total 40 KB -> 4 blocks/CU (16 waves/CU)

    const int tid = threadIdx.x, wid = tid >> 6, lane = tid & 63;
    const int l16 = lane & 15, lq = lane >> 4;

    // 1024 blocks, all co-resident at 4/CU -> static balance: 4 passes of 32
    // slots; slot a gets qt {31-a, 16+a, 15-a, a} -> per-slot total 64 tiles.
    // bh fixed per slot (K/V L2 reuse across the slot's 4 blocks).
    const int bid = blockIdx.x;
    const int xcd = bid & 7, t = bid >> 3;
    const int p = t >> 5, s = t & 31, a = s >> 2;
    const int qt = (p == 0) ? (31 - a) : (p == 1) ? (16 + a)
                 : (p == 2) ? (15 - a) : a;
    const int bh = xcd * 4 + (s & 3);
    const int h = bh & 15, bb = bh >> 4;
    const int q0 = qt * 64;
    const size_t kvbase = (size_t)bh * SEQ * DHEAD;
    const float slope2 = exp2f(-0.5f * (float)(h + 1)) * LOG2E;
    const int qr0 = wid * 16;
    const int lr8 = lane >> 3;
    const int colE = ((lane & 7) ^ lr8) << 3;

    // stage Q into QP (8 chunks of 8 rows)
    #pragma unroll
    for (int u = 0; u < 2; ++u) {
        int ch = u * 4 + wid;
        int row = ch * 8 + lr8;
        gload16(Qb + kvbase + (size_t)(q0 + row) * DHEAD + colE, QP + ch * 512);
    }
    // stage K/V tile 0
    #pragma unroll
    for (int u = 0; u < 2; ++u) {
        int ch = u * 4 + wid;
        int row = ch * 8 + lr8;
        gload16(Kb + kvbase + (size_t)row * DHEAD + colE, Ks[0] + ch * 512);
        gload16(Vb + kvbase + (size_t)row * SEQ  + colE, Vs[0] + ch * 512);
    }
    __syncthreads();

    // hoist Q fragments (each wave reads only its own 16 rows = its P strip)
    const int qrow = qr0 + l16;
    const bf16x8 aq0 = *(const bf16x8*)&QP[qrow * 64 + ((lq * 8) ^ ((qrow & 7) << 3))];
    const bf16x8 aq1 = *(const bf16x8*)&QP[qrow * 64 + ((32 + lq * 8) ^ ((qrow & 7) << 3))];

    // base ALiBi bias (jt=0): ct = slope2*((nf*16+l16) - qi); per-tile s = ct + jt*dtj
    float ct[4][4];
    #pragma unroll
    for (int r = 0; r < 4; ++r) {
        const int qi = q0 + qr0 + lq * 4 + r;
        #pragma unroll
        for (int nf = 0; nf < 4; ++nf)
            ct[r][nf] = slope2 * (float)(nf * 16 + l16 - qi);
    }
    const float dtj = slope2 * 64.f;

    float mrow[4], lrow[4];
    f32x4 accO[4];
    #pragma unroll
    for (int r = 0; r < 4; ++r) { mrow[r] = -1e30f; lrow[r] = 0.f; }
    #pragma unroll
    for (int j = 0; j < 4; ++j) accO[j] = f32x4{0.f, 0.f, 0.f, 0.f};

    int cur = 0;
    for (int jt = 0; jt <= qt; ++jt) {
        // async prefetch next K/V tile
        if (jt < qt) {
            const int jn = (jt + 1) * 64;
            #pragma unroll
            for (int u = 0; u < 2; ++u) {
                int ch = u * 4 + wid;
                int row = ch * 8 + lr8;
                gload16(Kb + kvbase + (size_t)(jn + row) * DHEAD + colE, Ks[cur ^ 1] + ch * 512);
                gload16(Vb + kvbase + (size_t)row * SEQ + jn + colE,     Vs[cur ^ 1] + ch * 512);
            }
        }

        // QK^T accumulator initialized with ALiBi bias (log2 domain)
        const float tb = dtj * (float)jt;
        f32x4 s[4];
        #pragma unroll
        for (int nf = 0; nf < 4; ++nf) {
            #pragma unroll
            for (int r = 0; r < 4; ++r) s[nf][r] = ct[r][nf] + tb;
        }
        if (jt == qt) {
            // diagonal tile: kill masked positions (tile-invariant pattern)
            #pragma unroll
            for (int nf = 0; nf < 4; ++nf)
                #pragma unroll
                for (int r = 0; r < 4; ++r)
                    if (nf * 16 + l16 > qr0 + lq * 4 + r) s[nf][r] = -3e38f;
        }

        __builtin_amdgcn_s_setprio(1);
        #pragma unroll
        for (int nf = 0; nf < 4; ++nf) {
            int kr = nf * 16 + l16;
            bf16x8 bk0 = *(const bf16x8*)&Ks[cur][kr * 64 + ((lq * 8) ^ ((kr & 7) << 3))];
            bf16x8 bk1 = *(const bf16x8*)&Ks[cur][kr * 64 + ((32 + lq * 8) ^ ((kr & 7) << 3))];
            s[nf] = __builtin_amdgcn_mfma_f32_16x16x32_bf16(aq0, bk0, s[nf], 0, 0, 0);
            s[nf] = __builtin_amdgcn_mfma_f32_16x16x32_bf16(aq1, bk1, s[nf], 0, 0, 0);
        }
        __builtin_amdgcn_s_setprio(0);

        // online softmax, log2 domain, DPP reductions, defer-max (THR=8)
        float rm[4];
        #pragma unroll
        for (int r = 0; r < 4; ++r)
            rm[r] = dpp_max16(fmaxf(fmaxf(s[0][r], s[1][r]), fmaxf(s[2][r], s[3][r])));
        bool need = (rm[0] > mrow[0] + 8.f) || (rm[1] > mrow[1] + 8.f) ||
                    (rm[2] > mrow[2] + 8.f) || (rm[3] > mrow[3] + 8.f);
        if (__any(need)) {
            #pragma unroll
            for (int r = 0; r < 4; ++r) {
                float mnew = fmaxf(mrow[r], rm[r]);
                float scale = __builtin_amdgcn_exp2f(mrow[r] - mnew);
                lrow[r] *= scale;
                mrow[r] = mnew;
                #pragma unroll
                for (int nf = 0; nf < 4; ++nf) accO[nf][r] *= scale;
            }
        }
        #pragma unroll
        for (int r = 0; r < 4; ++r) {
            float p0 = __builtin_amdgcn_exp2f(s[0][r] - mrow[r]);
            float p1 = __builtin_amdgcn_exp2f(s[1][r] - mrow[r]);
            float p2 = __builtin_amdgcn_exp2f(s[2][r] - mrow[r]);
            float p3 = __builtin_amdgcn_exp2f(s[3][r] - mrow[r]);
            const int prow = lq * 4 + r;
            const int pb = wid * 1024 + prow * 64;
            const int px = (prow & 7) << 3;
            QP[pb + ((l16     ) ^ px)] = (__bf16)p0;
            QP[pb + ((l16 + 16) ^ px)] = (__bf16)p1;
            QP[pb + ((l16 + 32) ^ px)] = (__bf16)p2;
            QP[pb + ((l16 + 48) ^ px)] = (__bf16)p3;
            lrow[r] += dpp_sum16((p0 + p1) + (p2 + p3));
        }

        // O += P V
        bf16x8 ap0 = *(const bf16x8*)&QP[wid * 1024 + l16 * 64 + ((lq * 8) ^ ((l16 & 7) << 3))];
        bf16x8 ap1 = *(const bf16x8*)&QP[wid * 1024 + l16 * 64 + ((32 + lq * 8) ^ ((l16 & 7) << 3))];
        __builtin_amdgcn_s_setprio(1);
        #pragma unroll
        for (int nf = 0; nf < 4; ++nf) {
            int vr = nf * 16 + l16;
            bf16x8 bv0 = *(const bf16x8*)&Vs[cur][vr * 64 + ((lq * 8) ^ ((vr & 7) << 3))];
            bf16x8 bv1 = *(const bf16x8*)&Vs[cur][vr * 64 + ((32 + lq * 8) ^ ((vr & 7) << 3))];
            accO[nf] = __builtin_amdgcn_mfma_f32_16x16x32_bf16(ap0, bv0, accO[nf], 0, 0, 0);
            accO[nf] = __builtin_amdgcn_mfma_f32_16x16x32_bf16(ap1, bv1, accO[nf], 0, 0, 0);
        }
        __builtin_amdgcn_s_setprio(0);

        __syncthreads();
        cur ^= 1;
    }

    #pragma unroll
    for (int r = 0; r < 4; ++r) {
        const float inv = __builtin_amdgcn_rcpf(lrow[r]);
        const int qi = q0 + qr0 + lq * 4 + r;
        #pragma unroll
        for (int nf = 0; nf < 4; ++nf) {
            int dh = nf * 16 + l16;
            Ob[(size_t)(bb * SEQ + qi) * DMODEL + h * DHEAD + dh] = (__bf16)(accO[nf][r] * inv);
        }
    }
}

extern "C" void kernel_launch(void* const* d_in, const int* in_sizes, int n_in,
                              void* d_out, int out_size, void* d_ws, size_t ws_size,
                              hipStream_t stream) {
    const float* x     = (const float*)d_in[0];
    const float* W_in  = (const float*)d_in[1];
    const float* b_in  = (const float*)d_in[2];
    const float* W_out = (const float*)d_in[3];
    const float* b_out = (const float*)d_in[4];

    float* out = (float*)d_out;
    float* kf  = out + (size_t)OUTSECT;
    float* vf  = out + 2 * (size_t)OUTSECT;

    __bf16* qb = (__bf16*)d_out;                   // scratch in d_out sec 0
    __bf16* xb = (__bf16*)d_out + (size_t)OUTSECT;

    __bf16* ob  = (__bf16*)d_ws;                   // 8 MB
    __bf16* kb  = ob + (size_t)OUTSECT;            // 8 MB
    __bf16* vb  = kb + (size_t)OUTSECT;            // 8 MB [B,H,Dh,L]
    __bf16* wti = vb + (size_t)OUTSECT;            // 6 MB
    __bf16* wto = wti + (size_t)N_QKV * KDIM;      // 2 MB

    cvt_all_k<<<3072, 256, 0, stream>>>(x, xb, W_in, wti, W_out, wto);

    gemm_bf<0, 4, 4><<<768, 256, 0, stream>>>(xb, wti, b_in,
        nullptr, kf, vf, qb, kb, vb, N_QKV / 128);

    attn_k<<<1024, 256, 0, stream>>>(qb, kb, vb, ob);

    gemm_bf<1, 4, 4><<<256, 256, 0, stream>>>(ob, wto, b_out,
        out, nullptr, nullptr, nullptr, nullptr, nullptr, DMODEL / 128);
}